// Round 5
// baseline (14618.137 us; speedup 1.0000x reference)
//
#include <hip/hip_runtime.h>

#define NT 256              // threads/block = 4 waves
#define GPB (NT / 2)        // graphs per block = 128
#define NB 262144

struct P {
  const float* node_feat; const float* edge_feat; const int* ei;
  const float* W_ne; const float* b_ne; const float* g_ne; const float* be_ne;
  const float* W_ee; const float* b_ee;
  const float* msg_W1; const float* msg_b1; const float* msg_W2; const float* msg_b2;
  const float* upd_W1; const float* upd_b1; const float* upd_g1; const float* upd_be1;
  const float* upd_W2; const float* upd_b2; const float* upd_g2; const float* upd_be2;
  const float* Wp; const float* bp; const float* gp; const float* bep;
  const float* mW1; const float* mb1; const float* mg1; const float* mbe1;
  const float* mW2; const float* mb2; const float* mg2; const float* mbe2;
  const float* mW3; const float* mb3; const float* mg3; const float* mbe3;
  const float* mW4; const float* mb4;
  float* out;
};

// 1/sqrt(1+1e-5)
#define INVC 0.9999950000374997f

__device__ __forceinline__ float sigm(float x) {
  return __builtin_amdgcn_rcpf(1.0f + __expf(-x));
}

// Pair lanes (2p, 2p+1) sit in the same quad -> quad_perm DPP exchanges.
// dpp_lo: every lane gets the even-of-pair value (quad_perm [0,0,2,2] = 0xA0)
// dpp_hi: every lane gets the odd-of-pair value  (quad_perm [1,1,3,3] = 0xF5)
// dpp_xor: every lane gets its partner's value   (quad_perm [1,0,3,2] = 0xB1)
__device__ __forceinline__ float dpp_lo(float v) {
  return __builtin_bit_cast(float, __builtin_amdgcn_update_dpp(
      0, __builtin_bit_cast(int, v), 0xA0, 0xF, 0xF, false));
}
__device__ __forceinline__ float dpp_hi(float v) {
  return __builtin_bit_cast(float, __builtin_amdgcn_update_dpp(
      0, __builtin_bit_cast(int, v), 0xF5, 0xF, 0xF, false));
}
__device__ __forceinline__ float dpp_xor1(float v) {
  return __builtin_bit_cast(float, __builtin_amdgcn_update_dpp(
      0, __builtin_bit_cast(int, v), 0xB1, 0xF, 0xF, false));
}

// own-half (8 regs) -> canonical 16-vector (both halves, k-ordered)
__device__ __forceinline__ void canon16(const float (&o)[8], float (&c)[16]) {
#pragma unroll
  for (int j = 0; j < 8; j++) { c[j] = dpp_lo(o[j]); c[8 + j] = dpp_hi(o[j]); }
}
__device__ __forceinline__ void canon64(const float (&o)[32], float (&c)[64]) {
#pragma unroll
  for (int j = 0; j < 32; j++) { c[j] = dpp_lo(o[j]); c[32 + j] = dpp_hi(o[j]); }
}

// own-half select of x[node] with uniform runtime node index (static reg indices)
__device__ __forceinline__ void sel5(const float (&x)[5][8], int n, float (&o)[8]) {
#pragma unroll
  for (int j = 0; j < 8; j++) {
    float v = x[0][j];
    v = (n == 1) ? x[1][j] : v;
    v = (n == 2) ? x[2][j] : v;
    v = (n == 3) ? x[3][j] : v;
    v = (n == 4) ? x[4][j] : v;
    o[j] = v;
  }
}

__device__ __forceinline__ void bias8(const float* b, int dbase, float (&a)[8]) {
  const float4* br = (const float4*)(b + dbase);
  float4 b0 = br[0], b1 = br[1];
  a[0] = b0.x; a[1] = b0.y; a[2] = b0.z; a[3] = b0.w;
  a[4] = b1.x; a[5] = b1.y; a[6] = b1.z; a[7] = b1.w;
}

template <int K>
__device__ __forceinline__ void gemm8(const float* W, int ld, int dbase,
                                      const float (&h)[K], float (&acc)[8]) {
#pragma unroll
  for (int k = 0; k < K; k++) {
    const float4* wr = (const float4*)(W + k * ld + dbase);
    float4 wa = wr[0], wb = wr[1];
    acc[0] = fmaf(h[k], wa.x, acc[0]); acc[1] = fmaf(h[k], wa.y, acc[1]);
    acc[2] = fmaf(h[k], wa.z, acc[2]); acc[3] = fmaf(h[k], wa.w, acc[3]);
    acc[4] = fmaf(h[k], wb.x, acc[4]); acc[5] = fmaf(h[k], wb.y, acc[5]);
    acc[6] = fmaf(h[k], wb.z, acc[6]); acc[7] = fmaf(h[k], wb.w, acc[7]);
  }
}

__device__ __forceinline__ void sigm8(float (&a)[8]) {
#pragma unroll
  for (int j = 0; j < 8; j++) a[j] = sigm(a[j]);
}

__device__ __forceinline__ void bnsig8(const float* gam, const float* bet, int dbase,
                                       float (&a)[8]) {
  const float4* gr = (const float4*)(gam + dbase);
  const float4* br = (const float4*)(bet + dbase);
  float4 g0 = gr[0], g1 = gr[1], b0 = br[0], b1 = br[1];
  a[0] = sigm(fmaf(g0.x * INVC, a[0], b0.x));
  a[1] = sigm(fmaf(g0.y * INVC, a[1], b0.y));
  a[2] = sigm(fmaf(g0.z * INVC, a[2], b0.z));
  a[3] = sigm(fmaf(g0.w * INVC, a[3], b0.w));
  a[4] = sigm(fmaf(g1.x * INVC, a[4], b1.x));
  a[5] = sigm(fmaf(g1.y * INVC, a[5], b1.y));
  a[6] = sigm(fmaf(g1.z * INVC, a[6], b1.z));
  a[7] = sigm(fmaf(g1.w * INVC, a[7], b1.w));
}

__device__ __forceinline__ void bias32(const float* b, int mbase, float (&a)[32]) {
#pragma unroll
  for (int q = 0; q < 8; q++) {
    float4 v = ((const float4*)(b + mbase))[q];
    a[q * 4 + 0] = v.x; a[q * 4 + 1] = v.y; a[q * 4 + 2] = v.z; a[q * 4 + 3] = v.w;
  }
}

template <int K>
__device__ __forceinline__ void gemm32(const float* W, int ld, int mbase,
                                       const float (&h)[K], float (&acc)[32]) {
#pragma unroll
  for (int k = 0; k < K; k++) {
    const float4* wr = (const float4*)(W + k * ld + mbase);
#pragma unroll
    for (int q = 0; q < 8; q++) {
      float4 w = wr[q];
      acc[q * 4 + 0] = fmaf(h[k], w.x, acc[q * 4 + 0]);
      acc[q * 4 + 1] = fmaf(h[k], w.y, acc[q * 4 + 1]);
      acc[q * 4 + 2] = fmaf(h[k], w.z, acc[q * 4 + 2]);
      acc[q * 4 + 3] = fmaf(h[k], w.w, acc[q * 4 + 3]);
    }
  }
}

__device__ __forceinline__ void bnsig32(const float* gam, const float* bet, int mbase,
                                        float (&a)[32]) {
#pragma unroll
  for (int q = 0; q < 8; q++) {
    float4 gv = ((const float4*)(gam + mbase))[q];
    float4 bv = ((const float4*)(bet + mbase))[q];
    a[q * 4 + 0] = sigm(fmaf(gv.x * INVC, a[q * 4 + 0], bv.x));
    a[q * 4 + 1] = sigm(fmaf(gv.y * INVC, a[q * 4 + 1], bv.y));
    a[q * 4 + 2] = sigm(fmaf(gv.z * INVC, a[q * 4 + 2], bv.z));
    a[q * 4 + 3] = sigm(fmaf(gv.w * INVC, a[q * 4 + 3], bv.w));
  }
}

__global__ __launch_bounds__(NT, 2) void gnn_kernel(P p) {
  const int t = threadIdx.x;
  const int pr = t >> 1;                 // pair (graph) within block
  const int g = blockIdx.x * GPB + pr;   // graph id
  const int d0 = (t & 1) * 8;            // own half of every 16-wide feature
  const int m0 = (t & 1) * 32;           // own half of every 64-wide MLP layer
  const int eo = (t & 1) * 2;            // own half of ED=4 edge embedding

  // edge indices -> SGPRs, statically indexed everywhere
  int se_[8], de_[8];
#pragma unroll
  for (int e = 0; e < 8; e++) {
    se_[e] = __builtin_amdgcn_readfirstlane(p.ei[e]);
    de_[e] = __builtin_amdgcn_readfirstlane(p.ei[8 + e]);
  }
  float dr_[5];
#pragma unroll
  for (int n = 0; n < 5; n++) {
    int c = 0;
#pragma unroll
    for (int e = 0; e < 8; e++) c += (de_[e] == n) ? 1 : 0;
    dr_[n] = 1.0f / (float)(c > 1 ? c : 1);
  }

  // ---------------- node encoder: x[n][own 8] ----------------
  float x[5][8];
  {
    float nf[5][7];
#pragma unroll
    for (int k = 0; k < 35; k++) nf[k / 7][k % 7] = p.node_feat[(size_t)g * 35 + k];
#pragma unroll
    for (int n = 0; n < 5; n++) {
      float acc[8];
      bias8(p.b_ne, d0, acc);
      gemm8<7>(p.W_ne, 16, d0, nf[n], acc);
      const float gn = p.g_ne[n] * INVC;
      const float bn_ = p.be_ne[n];
#pragma unroll
      for (int j = 0; j < 8; j++) x[n][j] = fmaf(gn, acc[j], bn_);
    }
  }

  // ---------------- edge encoder: ea_[e][own 2] (constant across layers) ----------------
  float ea_[8][2];
  {
    float ef[16];
    const float4* efv = (const float4*)(p.edge_feat + (size_t)g * 16);
#pragma unroll
    for (int q = 0; q < 4; q++) {
      float4 v = efv[q];
      ef[q * 4 + 0] = v.x; ef[q * 4 + 1] = v.y; ef[q * 4 + 2] = v.z; ef[q * 4 + 3] = v.w;
    }
#pragma unroll
    for (int e = 0; e < 8; e++)
#pragma unroll
      for (int j = 0; j < 2; j++)
        ea_[e][j] = fmaf(ef[2 * e], p.W_ee[eo + j],
                    fmaf(ef[2 * e + 1], p.W_ee[4 + eo + j], p.b_ee[eo + j]));
  }

  // ---------------- L message-passing layers ----------------
  float agg[5][8];
#pragma unroll 1
  for (int l = 0; l < 4; l++) {
    const float* mW1 = p.msg_W1 + l * 576;
    const float* mb1 = p.msg_b1 + l * 16;
    const float* mW2 = p.msg_W2 + l * 256;
    const float* mb2 = p.msg_b2 + l * 16;
    const float* uW1 = p.upd_W1 + l * 512;
    const float* ub1 = p.upd_b1 + l * 16;
    const float* ug1 = p.upd_g1 + l * 5;
    const float* ube1 = p.upd_be1 + l * 5;
    const float* uW2 = p.upd_W2 + l * 256;
    const float* ub2 = p.upd_b2 + l * 16;
    const float* ug2 = p.upd_g2 + l * 5;
    const float* ube2 = p.upd_be2 + l * 5;

#pragma unroll
    for (int n = 0; n < 5; n++)
#pragma unroll
      for (int j = 0; j < 8; j++) agg[n][j] = 0.f;

    // ---- phase A: per-edge messages, predicated scatter into agg ----
#pragma unroll
    for (int e = 0; e < 8; e++) {
      const int se = se_[e], de = de_[e];
      float ho[8], hi16[16], hj16[16];
      sel5(x, de, ho); canon16(ho, hi16);
      sel5(x, se, ho); canon16(ho, hj16);

      float m1[8];
      bias8(mb1, d0, m1);
      gemm8<16>(mW1, 16, d0, hi16, m1);
      gemm8<16>(mW1 + 256, 16, d0, hj16, m1);
      float ea4[4] = {dpp_lo(ea_[e][0]), dpp_lo(ea_[e][1]),
                      dpp_hi(ea_[e][0]), dpp_hi(ea_[e][1])};
      gemm8<4>(mW1 + 512, 16, d0, ea4, m1);
      sigm8(m1);

      float m1c[16]; canon16(m1, m1c);
      float m2[8];
      bias8(mb2, d0, m2);
      gemm8<16>(mW2, 16, d0, m1c, m2);
      sigm8(m2);

#pragma unroll
      for (int n = 0; n < 5; n++) {
        const float w = (de == n) ? 1.0f : 0.0f;
#pragma unroll
        for (int j = 0; j < 8; j++) agg[n][j] = fmaf(w, m2[j], agg[n][j]);
      }
    }

    // ---- phase B: per-node update (n fully unrolled -> static agg/x indices) ----
#pragma unroll
    for (int n = 0; n < 5; n++) {
      float anw[8];
#pragma unroll
      for (int j = 0; j < 8; j++) anw[j] = agg[n][j] * dr_[n];
      float an16[16]; canon16(anw, an16);
      float xn16[16]; canon16(x[n], xn16);

      float a1[8];
      bias8(ub1, d0, a1);
      gemm8<16>(uW1, 16, d0, xn16, a1);
      gemm8<16>(uW1 + 256, 16, d0, an16, a1);
      const float G1 = ug1[n] * INVC, B1 = ube1[n];
      float u1[8];
#pragma unroll
      for (int j = 0; j < 8; j++) u1[j] = sigm(fmaf(G1, a1[j], B1));

      float u1c[16]; canon16(u1, u1c);
      float a2[8];
      bias8(ub2, d0, a2);
      gemm8<16>(uW2, 16, d0, u1c, a2);
      const float G2 = ug2[n] * INVC, B2 = ube2[n];
#pragma unroll
      for (int j = 0; j < 8; j++) x[n][j] += sigm(fmaf(G2, a2[j], B2));
    }
  }

  // ---------------- pooling: p1[own 8] ----------------
  float p1[8];
  {
    float acc[8];
    bias8(p.bp, d0, acc);
#pragma unroll
    for (int n = 0; n < 5; n++) {
      float xc[16]; canon16(x[n], xc);
      gemm8<16>(p.Wp + n * 256, 16, d0, xc, acc);
    }
    bnsig8(p.gp, p.bep, d0, acc);
#pragma unroll
    for (int j = 0; j < 8; j++) p1[j] = acc[j];
  }

  // ---------------- MLP head, own 32 of 64 per layer ----------------
  float h[32], hc[64];
  {
    float p1c[16]; canon16(p1, p1c);
    float acc[32];
    bias32(p.mb1, m0, acc);
    gemm32<16>(p.mW1, 64, m0, p1c, acc);
    bnsig32(p.mg1, p.mbe1, m0, acc);
#pragma unroll
    for (int i = 0; i < 32; i++) h[i] = acc[i];
  }
  canon64(h, hc);
  {
    float acc[32];
    bias32(p.mb2, m0, acc);
    gemm32<64>(p.mW2, 64, m0, hc, acc);
    bnsig32(p.mg2, p.mbe2, m0, acc);
#pragma unroll
    for (int i = 0; i < 32; i++) h[i] = acc[i];
  }
  canon64(h, hc);
  {
    float acc[32];
    bias32(p.mb3, m0, acc);
    gemm32<64>(p.mW3, 64, m0, hc, acc);
    bnsig32(p.mg3, p.mbe3, m0, acc);
#pragma unroll
    for (int i = 0; i < 32; i++) h[i] = acc[i];
  }
  // mlp4: own 32-dot + pair reduce
  {
    float s0 = 0.f, s1 = 0.f, s2 = 0.f, s3 = 0.f;
#pragma unroll
    for (int k = 0; k < 32; k += 4) {
      s0 = fmaf(h[k + 0], p.mW4[m0 + k + 0], s0);
      s1 = fmaf(h[k + 1], p.mW4[m0 + k + 1], s1);
      s2 = fmaf(h[k + 2], p.mW4[m0 + k + 2], s2);
      s3 = fmaf(h[k + 3], p.mW4[m0 + k + 3], s3);
    }
    float s = (s0 + s1) + (s2 + s3);
    s += dpp_xor1(s);
    s += p.mb4[0];
    if ((t & 1) == 0) p.out[g] = s;
  }
}

extern "C" void kernel_launch(void* const* d_in, const int* in_sizes, int n_in,
                              void* d_out, int out_size, void* d_ws, size_t ws_size,
                              hipStream_t stream) {
  P p;
  p.node_feat = (const float*)d_in[0];
  p.edge_feat = (const float*)d_in[1];
  p.ei        = (const int*)d_in[2];
  p.W_ne  = (const float*)d_in[3];  p.b_ne  = (const float*)d_in[4];
  p.g_ne  = (const float*)d_in[5];  p.be_ne = (const float*)d_in[6];
  p.W_ee  = (const float*)d_in[7];  p.b_ee  = (const float*)d_in[8];
  p.msg_W1 = (const float*)d_in[9];  p.msg_b1 = (const float*)d_in[10];
  p.msg_W2 = (const float*)d_in[11]; p.msg_b2 = (const float*)d_in[12];
  p.upd_W1 = (const float*)d_in[13]; p.upd_b1 = (const float*)d_in[14];
  p.upd_g1 = (const float*)d_in[15]; p.upd_be1 = (const float*)d_in[16];
  p.upd_W2 = (const float*)d_in[17]; p.upd_b2 = (const float*)d_in[18];
  p.upd_g2 = (const float*)d_in[19]; p.upd_be2 = (const float*)d_in[20];
  p.Wp  = (const float*)d_in[21]; p.bp  = (const float*)d_in[22];
  p.gp  = (const float*)d_in[23]; p.bep = (const float*)d_in[24];
  p.mW1 = (const float*)d_in[25]; p.mb1 = (const float*)d_in[26];
  p.mg1 = (const float*)d_in[27]; p.mbe1 = (const float*)d_in[28];
  p.mW2 = (const float*)d_in[29]; p.mb2 = (const float*)d_in[30];
  p.mg2 = (const float*)d_in[31]; p.mbe2 = (const float*)d_in[32];
  p.mW3 = (const float*)d_in[33]; p.mb3 = (const float*)d_in[34];
  p.mg3 = (const float*)d_in[35]; p.mbe3 = (const float*)d_in[36];
  p.mW4 = (const float*)d_in[37]; p.mb4 = (const float*)d_in[38];
  p.out = (float*)d_out;

  hipLaunchKernelGGL(gnn_kernel, dim3(NB / GPB), dim3(NT), 0, stream, p);
}

// Round 6
// 12196.590 us; speedup vs baseline: 1.1985x; 1.1985x over previous
//
#include <hip/hip_runtime.h>

#define NT 64
#define NB 262144

struct P {
  const float* node_feat; const float* edge_feat; const int* ei;
  const float* W_ne; const float* b_ne; const float* g_ne; const float* be_ne;
  const float* W_ee; const float* b_ee;
  const float* msg_W1; const float* msg_b1; const float* msg_W2; const float* msg_b2;
  const float* upd_W1; const float* upd_b1; const float* upd_g1; const float* upd_be1;
  const float* upd_W2; const float* upd_b2; const float* upd_g2; const float* upd_be2;
  const float* Wp; const float* bp; const float* gp; const float* bep;
  const float* mW1; const float* mb1; const float* mg1; const float* mbe1;
  const float* mW2; const float* mb2; const float* mg2; const float* mbe2;
  const float* mW3; const float* mb3; const float* mg3; const float* mbe3;
  const float* mW4; const float* mb4;
  float* out;
};

// 1/sqrt(1+1e-5)
#define INVC 0.9999950000374997f

__device__ __forceinline__ float sigm(float x) {
  return __builtin_amdgcn_rcpf(1.0f + __expf(-x));
}

// copy x[n] -> o with n a wave-uniform runtime index; static register indices only
__device__ __forceinline__ void sel5(const float (&x)[5][16], int n, float (&o)[16]) {
#pragma unroll
  for (int j = 0; j < 16; j++) {
    float v = x[0][j];
    v = (n == 1) ? x[1][j] : v;
    v = (n == 2) ? x[2][j] : v;
    v = (n == 3) ? x[3][j] : v;
    v = (n == 4) ? x[4][j] : v;
    o[j] = v;
  }
}

// LDS: 80 rows * 64 cols * 4B = 20 KiB/block.
//  - during GNN layers: agg[n][d] at row n*16+d (column t = this thread's graph)
//  - during MLP head:   h[64] at rows 0..63
// Column-per-thread => bank = t%32 (2 lanes/bank, free), zero barriers.
__global__ __launch_bounds__(NT, 2) void gnn_kernel(P p) {
  const int t = threadIdx.x;
  const int g = blockIdx.x * NT + t;

  __shared__ float as_[80][NT];

  // ---------------- edge indices -> SGPRs (statically indexed everywhere) ----------------
  int se_[8], de_[8];
#pragma unroll
  for (int e = 0; e < 8; e++) {
    se_[e] = __builtin_amdgcn_readfirstlane(p.ei[e]);
    de_[e] = __builtin_amdgcn_readfirstlane(p.ei[8 + e]);
  }
  float dr_[5];
#pragma unroll
  for (int n = 0; n < 5; n++) {
    int c = 0;
#pragma unroll
    for (int e = 0; e < 8; e++) c += (de_[e] == n) ? 1 : 0;
    dr_[n] = 1.0f / (float)(c > 1 ? c : 1);
  }

  // ---------------- node encoder: x[5][16] in REGISTERS ----------------
  float x[5][16];
#pragma unroll
  for (int n = 0; n < 5; n++) {
    float nfv[7];
#pragma unroll
    for (int k = 0; k < 7; k++) nfv[k] = p.node_feat[(size_t)g * 35 + n * 7 + k];
    const float gn = p.g_ne[n] * INVC;
    const float bn_ = p.be_ne[n];
#pragma unroll
    for (int d = 0; d < 16; d++) {
      float a = p.b_ne[d];
#pragma unroll
      for (int k = 0; k < 7; k++) a = fmaf(nfv[k], p.W_ne[k * 16 + d], a);
      x[n][d] = fmaf(gn, a, bn_);
    }
  }

  // ---------------- raw edge features in registers ----------------
  float ef[16];
  {
    const float4* efv = reinterpret_cast<const float4*>(p.edge_feat + (size_t)g * 16);
#pragma unroll
    for (int q = 0; q < 4; q++) {
      float4 v = efv[q];
      ef[q * 4 + 0] = v.x; ef[q * 4 + 1] = v.y;
      ef[q * 4 + 2] = v.z; ef[q * 4 + 3] = v.w;
    }
  }

  // ---------------- L message-passing layers ----------------
#pragma unroll 1
  for (int l = 0; l < 4; l++) {
    const float* mW1 = p.msg_W1 + l * 576;
    const float* mb1 = p.msg_b1 + l * 16;
    const float* mW2 = p.msg_W2 + l * 256;
    const float* mb2 = p.msg_b2 + l * 16;
    const float* uW1 = p.upd_W1 + l * 512;
    const float* ub1 = p.upd_b1 + l * 16;
    const float* ug1 = p.upd_g1 + l * 5;
    const float* ube1 = p.upd_be1 + l * 5;
    const float* uW2 = p.upd_W2 + l * 256;
    const float* ub2 = p.upd_b2 + l * 16;
    const float* ug2 = p.upd_g2 + l * 5;
    const float* ube2 = p.upd_be2 + l * 5;

    // zero agg rows (own column only)
#pragma unroll
    for (int r = 0; r < 80; r++) as_[r][t] = 0.f;

    // ---- phase A: per-edge messages; pure register/SMEM FMA stream, LDS only at tail ----
#pragma unroll
    for (int e = 0; e < 8; e++) {
      const int se = se_[e], de = de_[e];
      float hi[16], hj[16];
      sel5(x, de, hi);
      sel5(x, se, hj);

      float m1[16];
#pragma unroll
      for (int d = 0; d < 16; d++) m1[d] = mb1[d];
#pragma unroll
      for (int k = 0; k < 16; k++)
#pragma unroll
        for (int d = 0; d < 16; d++) m1[d] = fmaf(hi[k], mW1[k * 16 + d], m1[d]);
#pragma unroll
      for (int k = 0; k < 16; k++)
#pragma unroll
        for (int d = 0; d < 16; d++) m1[d] = fmaf(hj[k], mW1[(16 + k) * 16 + d], m1[d]);
      {
        const float e0 = ef[2 * e], e1 = ef[2 * e + 1];
#pragma unroll
        for (int j = 0; j < 4; j++) {
          float ea = fmaf(e0, p.W_ee[j], fmaf(e1, p.W_ee[4 + j], p.b_ee[j]));
#pragma unroll
          for (int d = 0; d < 16; d++) m1[d] = fmaf(ea, mW1[(32 + j) * 16 + d], m1[d]);
        }
      }
#pragma unroll
      for (int d = 0; d < 16; d++) m1[d] = sigm(m1[d]);

      // m2 -> accumulate into LDS agg row (runtime uniform row base, fine for LDS)
#pragma unroll
      for (int d = 0; d < 16; d++) {
        float a = mb2[d];
#pragma unroll
        for (int k = 0; k < 16; k++) a = fmaf(m1[k], mW2[k * 16 + d], a);
        as_[de * 16 + d][t] += sigm(a);
      }
    }

    // ---- phase B: per-node update, x[n] += u2 (n unrolled -> all x indices static) ----
#pragma unroll
    for (int n = 0; n < 5; n++) {
      float an[16];
#pragma unroll
      for (int k = 0; k < 16; k++) an[k] = as_[n * 16 + k][t] * dr_[n];

      float a1[16];
#pragma unroll
      for (int d = 0; d < 16; d++) a1[d] = ub1[d];
#pragma unroll
      for (int k = 0; k < 16; k++)
#pragma unroll
        for (int d = 0; d < 16; d++) a1[d] = fmaf(x[n][k], uW1[k * 16 + d], a1[d]);
#pragma unroll
      for (int k = 0; k < 16; k++)
#pragma unroll
        for (int d = 0; d < 16; d++) a1[d] = fmaf(an[k], uW1[(16 + k) * 16 + d], a1[d]);

      const float G1 = ug1[n] * INVC, B1 = ube1[n];
      float u1[16];
#pragma unroll
      for (int d = 0; d < 16; d++) u1[d] = sigm(fmaf(G1, a1[d], B1));

      const float G2 = ug2[n] * INVC, B2 = ube2[n];
#pragma unroll
      for (int d = 0; d < 16; d++) {
        float a = ub2[d];
#pragma unroll
        for (int k = 0; k < 16; k++) a = fmaf(u1[k], uW2[k * 16 + d], a);
        x[n][d] += sigm(fmaf(G2, a, B2));
      }
    }
  }

  // ---------------- pooling: p1 = sigmoid(bnc(x.reshape(80) @ Wp + bp)) ----------------
  float p1[16];
  {
    float acc[16];
#pragma unroll
    for (int d = 0; d < 16; d++) acc[d] = p.bp[d];
#pragma unroll
    for (int n = 0; n < 5; n++)
#pragma unroll
      for (int k = 0; k < 16; k++) {
        const float xv = x[n][k];
#pragma unroll
        for (int d = 0; d < 16; d++)
          acc[d] = fmaf(xv, p.Wp[(n * 16 + k) * 16 + d], acc[d]);
      }
#pragma unroll
    for (int d = 0; d < 16; d++)
      p1[d] = sigm(fmaf(p.gp[d] * INVC, acc[d], p.bep[d]));
  }

  // ---------------- MLP head (x dead; registers free; h lives in LDS rows 0..63) ----------------
  // mlp1: p1(regs) -> rows 0..63
  {
    float acc[4][16];
#pragma unroll
    for (int c = 0; c < 4; c++)
#pragma unroll
      for (int d = 0; d < 16; d++) acc[c][d] = p.mb1[c * 16 + d];
#pragma unroll 2
    for (int k = 0; k < 16; k++) {
      const float hv = p1[k];
#pragma unroll
      for (int c = 0; c < 4; c++)
#pragma unroll
        for (int d = 0; d < 16; d++)
          acc[c][d] = fmaf(hv, p.mW1[k * 64 + c * 16 + d], acc[c][d]);
    }
#pragma unroll
    for (int c = 0; c < 4; c++)
#pragma unroll
      for (int d = 0; d < 16; d++)
        as_[c * 16 + d][t] = sigm(fmaf(p.mg1[c * 16 + d] * INVC, acc[c][d], p.mbe1[c * 16 + d]));
  }
  // mlp2: rows 0..63 -> rows 0..63 (single k-pass with 64 accumulators, then write)
  {
    float acc[4][16];
#pragma unroll
    for (int c = 0; c < 4; c++)
#pragma unroll
      for (int d = 0; d < 16; d++) acc[c][d] = p.mb2[c * 16 + d];
#pragma unroll 2
    for (int k = 0; k < 64; k++) {
      const float hv = as_[k][t];
#pragma unroll
      for (int c = 0; c < 4; c++)
#pragma unroll
        for (int d = 0; d < 16; d++)
          acc[c][d] = fmaf(hv, p.mW2[k * 64 + c * 16 + d], acc[c][d]);
    }
#pragma unroll
    for (int c = 0; c < 4; c++)
#pragma unroll
      for (int d = 0; d < 16; d++)
        as_[c * 16 + d][t] = sigm(fmaf(p.mg2[c * 16 + d] * INVC, acc[c][d], p.mbe2[c * 16 + d]));
  }
  // mlp3: rows 0..63 -> rows 0..63
  {
    float acc[4][16];
#pragma unroll
    for (int c = 0; c < 4; c++)
#pragma unroll
      for (int d = 0; d < 16; d++) acc[c][d] = p.mb3[c * 16 + d];
#pragma unroll 2
    for (int k = 0; k < 64; k++) {
      const float hv = as_[k][t];
#pragma unroll
      for (int c = 0; c < 4; c++)
#pragma unroll
        for (int d = 0; d < 16; d++)
          acc[c][d] = fmaf(hv, p.mW3[k * 64 + c * 16 + d], acc[c][d]);
    }
#pragma unroll
    for (int c = 0; c < 4; c++)
#pragma unroll
      for (int d = 0; d < 16; d++)
        as_[c * 16 + d][t] = sigm(fmaf(p.mg3[c * 16 + d] * INVC, acc[c][d], p.mbe3[c * 16 + d]));
  }
  // mlp4: rows 0..63 -> out (4 partial sums)
  {
    float a0 = p.mb4[0], a1 = 0.f, a2 = 0.f, a3 = 0.f;
#pragma unroll 2
    for (int k = 0; k < 16; k++) {
      a0 = fmaf(as_[k * 4 + 0][t], p.mW4[k * 4 + 0], a0);
      a1 = fmaf(as_[k * 4 + 1][t], p.mW4[k * 4 + 1], a1);
      a2 = fmaf(as_[k * 4 + 2][t], p.mW4[k * 4 + 2], a2);
      a3 = fmaf(as_[k * 4 + 3][t], p.mW4[k * 4 + 3], a3);
    }
    p.out[g] = (a0 + a1) + (a2 + a3);
  }
}

extern "C" void kernel_launch(void* const* d_in, const int* in_sizes, int n_in,
                              void* d_out, int out_size, void* d_ws, size_t ws_size,
                              hipStream_t stream) {
  P p;
  p.node_feat = (const float*)d_in[0];
  p.edge_feat = (const float*)d_in[1];
  p.ei        = (const int*)d_in[2];
  p.W_ne  = (const float*)d_in[3];  p.b_ne  = (const float*)d_in[4];
  p.g_ne  = (const float*)d_in[5];  p.be_ne = (const float*)d_in[6];
  p.W_ee  = (const float*)d_in[7];  p.b_ee  = (const float*)d_in[8];
  p.msg_W1 = (const float*)d_in[9];  p.msg_b1 = (const float*)d_in[10];
  p.msg_W2 = (const float*)d_in[11]; p.msg_b2 = (const float*)d_in[12];
  p.upd_W1 = (const float*)d_in[13]; p.upd_b1 = (const float*)d_in[14];
  p.upd_g1 = (const float*)d_in[15]; p.upd_be1 = (const float*)d_in[16];
  p.upd_W2 = (const float*)d_in[17]; p.upd_b2 = (const float*)d_in[18];
  p.upd_g2 = (const float*)d_in[19]; p.upd_be2 = (const float*)d_in[20];
  p.Wp  = (const float*)d_in[21]; p.bp  = (const float*)d_in[22];
  p.gp  = (const float*)d_in[23]; p.bep = (const float*)d_in[24];
  p.mW1 = (const float*)d_in[25]; p.mb1 = (const float*)d_in[26];
  p.mg1 = (const float*)d_in[27]; p.mbe1 = (const float*)d_in[28];
  p.mW2 = (const float*)d_in[29]; p.mb2 = (const float*)d_in[30];
  p.mg2 = (const float*)d_in[31]; p.mbe2 = (const float*)d_in[32];
  p.mW3 = (const float*)d_in[33]; p.mb3 = (const float*)d_in[34];
  p.mg3 = (const float*)d_in[35]; p.mbe3 = (const float*)d_in[36];
  p.mW4 = (const float*)d_in[37]; p.mb4 = (const float*)d_in[38];
  p.out = (float*)d_out;

  hipLaunchKernelGGL(gnn_kernel, dim3(NB / NT), dim3(NT), 0, stream, p);
}